// Round 13
// baseline (41.160 us; speedup 1.0000x reference)
//
#include <hip/hip_runtime.h>
#include <math.h>

#define NC     10
#define NCP    12     // padded row stride (floats); 48B rows, 16B aligned
#define NM     128
#define NGEN   4
#define NPT    1023
#define NTREES 1024

#define RCPF(x) __builtin_amdgcn_rcpf(x)
#define WAVE_FENCE() __builtin_amdgcn_wave_barrier()

struct F12 { float4 a, b, c; };

__device__ __forceinline__ F12 ld12(const float* p) {
    F12 r; const float4* q = (const float4*)p;
    r.a = q[0]; r.b = q[1]; r.c = q[2]; return r;
}
__device__ __forceinline__ void unpack10(float* t, const F12& r) {
    t[0] = r.a.x; t[1] = r.a.y; t[2] = r.a.z; t[3] = r.a.w;
    t[4] = r.b.x; t[5] = r.b.y; t[6] = r.b.z; t[7] = r.b.w;
    t[8] = r.c.x; t[9] = r.c.y;
}
__device__ __forceinline__ void fma10(float* t, const F12& c, float s) {
    t[0] += c.a.x * s; t[1] += c.a.y * s; t[2] += c.a.z * s; t[3] += c.a.w * s;
    t[4] += c.b.x * s; t[5] += c.b.y * s; t[6] += c.b.z * s; t[7] += c.b.w * s;
    t[8] += c.c.x * s; t[9] += c.c.y * s;
}
__device__ __forceinline__ void mul10(float* t, const F12& r) {
    t[0] *= r.a.x; t[1] *= r.a.y; t[2] *= r.a.z; t[3] *= r.a.w;
    t[4] *= r.b.x; t[5] *= r.b.y; t[6] *= r.b.z; t[7] *= r.b.w;
    t[8] *= r.c.x; t[9] *= r.c.y;
}
__device__ __forceinline__ float sum10(const float* v) {
    return (((v[0] + v[1]) + (v[2] + v[3])) + ((v[4] + v[5]) + (v[6] + v[7]))) + (v[8] + v[9]);
}

// fused 2-level tail step, in place (stride 64), telescoped (1 log, 1 rcp).
// A columns read from LDS once per j (shared by both child accumulators).
__device__ __forceinline__ float fused_step_ip(const float (*sACol)[NCP], const float (*sBT)[NCP],
                                               float* buf, int l,
                                               int xc0, int xc1, int xp)
{
    float t0[NC], t1[NC];
    #pragma unroll
    for (int i = 0; i < NC; ++i) { t0[i] = 0.f; t1[i] = 0.f; }
    #pragma unroll
    for (int j = 0; j < NC; ++j) {
        float4 gv = *(const float4*)(buf + j * 64 + 4 * l);
        F12 aj = ld12(&sACol[j][0]);
        fma10(t0, aj, gv.x + gv.y);
        fma10(t1, aj, gv.z + gv.w);
    }
    mul10(t0, ld12(&sBT[xc0][0]));
    mul10(t1, ld12(&sBT[xc1][0]));
    const float nu0 = sum10(t0), nu1 = sum10(t1);
    float tp[NC];
    #pragma unroll
    for (int i = 0; i < NC; ++i) tp[i] = 0.f;
    #pragma unroll
    for (int j = 0; j < NC; ++j) fma10(tp, ld12(&sACol[j][0]), t0[j] * nu1 + t1[j] * nu0);
    mul10(tp, ld12(&sBT[xp][0]));
    const float nup = sum10(tp);
    const float rp = RCPF(nup);
    #pragma unroll
    for (int j = 0; j < NC; ++j) buf[j * 64 + l] = tp[j] * rp;
    return __logf(nup);   // = log nu_p + log nu0 + log nu1 exactly
}

// ---------------- single fused kernel ----------------
// block = 256 threads = 4 (tree,g) units (one wave each, same g per block).
// Lane = one L6 subtree. HEAD USES BATCHED A-SWEEPS: one pass over A's 10
// columns feeds 4 (L8) / 2 (L7) / 1 (L6) accumulators, cutting the dominant
// LDS traffic (uniform A-column reloads) from 210 to 90 ds_read_b128/wave.
// Telescoped normalization (5 rcp+log per lane head) kept from R11 — exact.
// NO launch_bounds min-waves (R7: caps VGPR -> 600MB scratch spill).
__global__ __launch_bounds__(256)
void htmm_fused(const int* __restrict__ x,
                const float* __restrict__ A,
                const float* __restrict__ B,
                const float* __restrict__ Pi,
                float* __restrict__ out)
{
    __shared__ __align__(16) float sACol[NC][NCP];   // 0.5*smA[i][j], col-major
    __shared__ __align__(16) float sBT[NM][NCP];     // smB^T rows
    __shared__ __align__(16) float sBTpi[NM][NCP];   // pi (.) smB^T rows (leaves)
    __shared__ __align__(16) float sPiP[NCP];
    __shared__ __align__(16) float sB6[4][NC][64];   // per-unit SoA; tail in place

    const int bid = blockIdx.x;
    const int g = bid >> 8;
    const int treeBase = (bid & 255) * 4;
    const int tid = threadIdx.x;
    const int u = tid >> 6, lane = tid & 63;

    const int tree = treeBase + u;
    const int tb = tree * NPT;

    // ---- hoisted observation-index loads (overlap setup latency) ----
    int xl[8];
    #pragma unroll
    for (int k = 0; k < 8; ++k) xl[k] = x[tb + 511 + 8 * lane + k];
    int x8v[4];
    #pragma unroll
    for (int c = 0; c < 4; ++c) x8v[c] = x[tb + 255 + 4 * lane + c];
    const int x7a = x[tb + 127 + 2 * lane];
    const int x7b = x[tb + 128 + 2 * lane];
    const int x6v = x[tb + 63 + lane];

    // ---- parameter softmaxes (B: no-max — |2.5*N| small, exp safe; R11-validated) ----
    for (int c = u; c < NC; c += 4) {
        float e0 = __expf(B[(c * NM + lane) * NGEN + g]);
        float e1 = __expf(B[(c * NM + lane + 64) * NGEN + g]);
        float sm = e0 + e1;
        #pragma unroll
        for (int off = 32; off; off >>= 1) sm += __shfl_xor(sm, off);
        const float rs = 1.f / sm;
        sBT[lane][c]      = e0 * rs;
        sBT[lane + 64][c] = e1 * rs;
    }
    if (tid >= 128 && tid < 128 + NC) {   // A column softmax on wave 2
        const int j = tid - 128;
        float col[NC], mx = -1e30f;
        #pragma unroll
        for (int i = 0; i < NC; ++i) { col[i] = A[(i * NC + j) * NGEN + g]; mx = fmaxf(mx, col[i]); }
        float sm = 0.f;
        #pragma unroll
        for (int i = 0; i < NC; ++i) { col[i] = __expf(col[i] - mx); sm += col[i]; }
        const float rs = 0.5f / sm;
        #pragma unroll
        for (int i = 0; i < NC; ++i) sACol[j][i] = col[i] * rs;
    }
    if (tid == 192) {                     // Pi softmax on wave 3
        float col[NC], mx = -1e30f;
        #pragma unroll
        for (int i = 0; i < NC; ++i) { col[i] = Pi[i * NGEN + g]; mx = fmaxf(mx, col[i]); }
        float sm = 0.f;
        #pragma unroll
        for (int i = 0; i < NC; ++i) { col[i] = __expf(col[i] - mx); sm += col[i]; }
        const float rs = 1.f / sm;
        #pragma unroll
        for (int i = 0; i < NC; ++i) sPiP[i] = col[i] * rs;
    }
    __syncthreads();
    if (tid < NM) {   // sBTpi[m][c] = pi[c] * sBT[m][c]
        F12 pi = ld12(sPiP);
        F12 r  = ld12(&sBT[tid][0]);
        sBTpi[tid][0] = pi.a.x * r.a.x; sBTpi[tid][1] = pi.a.y * r.a.y;
        sBTpi[tid][2] = pi.a.z * r.a.z; sBTpi[tid][3] = pi.a.w * r.a.w;
        sBTpi[tid][4] = pi.b.x * r.b.x; sBTpi[tid][5] = pi.b.y * r.b.y;
        sBTpi[tid][6] = pi.b.z * r.b.z; sBTpi[tid][7] = pi.b.w * r.b.w;
        sBTpi[tid][8] = pi.c.x * r.c.x; sBTpi[tid][9] = pi.c.y * r.c.y;
    }
    __syncthreads();

    float llacc = 0.f;

    // ---- leaf pairs: 4 telescoped pair-sums (scale nu0*nu1 each) ----
    float sc[4][NC];
    #pragma unroll
    for (int k = 0; k < 4; ++k) {
        float b0[NC], b1[NC];
        unpack10(b0, ld12(&sBTpi[xl[2 * k]][0]));
        unpack10(b1, ld12(&sBTpi[xl[2 * k + 1]][0]));
        const float nu0 = sum10(b0), nu1 = sum10(b1);
        #pragma unroll
        for (int j = 0; j < NC; ++j) sc[k][j] = b0[j] * nu1 + b1[j] * nu0;
    }

    // ---- L8: ONE A-sweep, 4 accumulators ----
    float t[4][NC];
    #pragma unroll
    for (int k = 0; k < 4; ++k)
        #pragma unroll
        for (int i = 0; i < NC; ++i) t[k][i] = 0.f;
    #pragma unroll
    for (int j = 0; j < NC; ++j) {
        F12 aj = ld12(&sACol[j][0]);
        #pragma unroll
        for (int k = 0; k < 4; ++k) fma10(t[k], aj, sc[k][j]);
    }
    // finish L8 nodes: one log covers {leaf,leaf,L8} per k; normalize exactly
    #pragma unroll
    for (int k = 0; k < 4; ++k) {
        mul10(t[k], ld12(&sBT[x8v[k]][0]));
        const float nu = sum10(t[k]);
        llacc += __logf(nu);
        const float r = RCPF(nu);
        #pragma unroll
        for (int j = 0; j < NC; ++j) t[k][j] *= r;
    }

    // ---- L7: ONE A-sweep, 2 accumulators (kept unnormalized) ----
    #pragma unroll
    for (int j = 0; j < NC; ++j) { sc[0][j] = t[0][j] + t[1][j]; sc[1][j] = t[2][j] + t[3][j]; }
    float u7a[NC], u7b[NC];
    #pragma unroll
    for (int i = 0; i < NC; ++i) { u7a[i] = 0.f; u7b[i] = 0.f; }
    #pragma unroll
    for (int j = 0; j < NC; ++j) {
        F12 aj = ld12(&sACol[j][0]);
        fma10(u7a, aj, sc[0][j]);
        fma10(u7b, aj, sc[1][j]);
    }
    mul10(u7a, ld12(&sBT[x7a][0]));
    mul10(u7b, ld12(&sBT[x7b][0]));
    const float nu7a = sum10(u7a), nu7b = sum10(u7b);

    // ---- L6: ONE A-sweep, telescoped {L7a,L7b,L6} -> one log, one rcp ----
    #pragma unroll
    for (int j = 0; j < NC; ++j) sc[0][j] = u7a[j] * nu7b + u7b[j] * nu7a;
    float t6[NC];
    #pragma unroll
    for (int i = 0; i < NC; ++i) t6[i] = 0.f;
    #pragma unroll
    for (int j = 0; j < NC; ++j) fma10(t6, ld12(&sACol[j][0]), sc[0][j]);
    mul10(t6, ld12(&sBT[x6v][0]));
    const float nup = sum10(t6);
    llacc += __logf(nup);
    const float rp = RCPF(nup);
    #pragma unroll
    for (int j = 0; j < NC; ++j) sB6[u][j][lane] = t6[j] * rp;

    // ---- tail: levels 5..0, wave-local, in place in sB6 ----
    WAVE_FENCE();
    float lla = 0.f;
    if (lane < 16)
        lla = fused_step_ip(sACol, sBT, &sB6[u][0][0], lane,
                            x[tb + 31 + 2 * lane], x[tb + 32 + 2 * lane],
                            x[tb + 15 + lane]);
    llacc += lla;
    WAVE_FENCE();
    float llb = 0.f;
    if (lane < 4)
        llb = fused_step_ip(sACol, sBT, &sB6[u][0][0], lane,
                            x[tb + 7 + 2 * lane], x[tb + 8 + 2 * lane],
                            x[tb + 3 + lane]);
    llacc += llb;
    WAVE_FENCE();
    if (lane == 0)
        llacc += fused_step_ip(sACol, sBT, &sB6[u][0][0], 0,
                               x[tb + 1], x[tb + 2], x[tb + 0]);

    // ---- full-wave reduce; lane 0 writes the unit's output ----
    #pragma unroll
    for (int off = 32; off; off >>= 1) llacc += __shfl_down(llacc, off);
    if (lane == 0) out[tree * NGEN + g] = llacc;
}

extern "C" void kernel_launch(void* const* d_in, const int* in_sizes, int n_in,
                              void* d_out, int out_size, void* d_ws, size_t ws_size,
                              hipStream_t stream) {
    const int*   x  = (const int*)d_in[0];
    const float* A  = (const float*)d_in[1];
    const float* B  = (const float*)d_in[2];
    const float* Pi = (const float*)d_in[3];
    float* out = (float*)d_out;
    htmm_fused<<<NTREES, 256, 0, stream>>>(x, A, B, Pi, out);
}

// Round 14
// 26.680 us; speedup vs baseline: 1.5427x; 1.5427x over previous
//
#include <hip/hip_runtime.h>
#include <math.h>

#define NC     10
#define NCP    12     // padded row stride (floats); 48B rows, 16B aligned
#define NM     128
#define NGEN   4
#define NPT    1023
#define NTREES 1024

#define RCPF(x) __builtin_amdgcn_rcpf(x)
#define WAVE_FENCE() __builtin_amdgcn_wave_barrier()

struct F12 { float4 a, b, c; };

__device__ __forceinline__ F12 ld12(const float* p) {
    F12 r; const float4* q = (const float4*)p;
    r.a = q[0]; r.b = q[1]; r.c = q[2]; return r;
}
__device__ __forceinline__ void unpack10(float* t, const F12& r) {
    t[0] = r.a.x; t[1] = r.a.y; t[2] = r.a.z; t[3] = r.a.w;
    t[4] = r.b.x; t[5] = r.b.y; t[6] = r.b.z; t[7] = r.b.w;
    t[8] = r.c.x; t[9] = r.c.y;
}
__device__ __forceinline__ void fma10(float* t, const F12& c, float s) {
    t[0] += c.a.x * s; t[1] += c.a.y * s; t[2] += c.a.z * s; t[3] += c.a.w * s;
    t[4] += c.b.x * s; t[5] += c.b.y * s; t[6] += c.b.z * s; t[7] += c.b.w * s;
    t[8] += c.c.x * s; t[9] += c.c.y * s;
}
__device__ __forceinline__ void mul10(float* t, const F12& r) {
    t[0] *= r.a.x; t[1] *= r.a.y; t[2] *= r.a.z; t[3] *= r.a.w;
    t[4] *= r.b.x; t[5] *= r.b.y; t[6] *= r.b.z; t[7] *= r.b.w;
    t[8] *= r.c.x; t[9] *= r.c.y;
}
__device__ __forceinline__ float sum10(const float* v) {
    return (((v[0] + v[1]) + (v[2] + v[3])) + ((v[4] + v[5]) + (v[6] + v[7]))) + (v[8] + v[9]);
}

// 7-node telescoped half-subtree: {4 leaves, 2 L8 (unnormalized), L7}.
// ONE log + ONE rcp for all seven nodes; b7out = exactly-normalized L7 beta.
// Scale bookkeeping: nu7' = nu7 * nu8a' * nu8b', nu8' = nu8 * nu_leaf0 * nu_leaf1;
// log(nu7') telescopes all seven ll terms; normalization divides all scales out.
__device__ __forceinline__ float half_subtree(const F12* acol,
                                              const float (*sBT)[NCP],
                                              const float (*sBTpi)[NCP],
                                              int xl0, int xl1, int xl2, int xl3,
                                              int x8a, int x8b, int x7, float* b7out)
{
    float b0[NC], b1[NC], sc[NC], t8a[NC], t8b[NC];

    // leaf pair a -> unnormalized L8a
    unpack10(b0, ld12(&sBTpi[xl0][0]));
    unpack10(b1, ld12(&sBTpi[xl1][0]));
    float nu0 = sum10(b0), nu1 = sum10(b1);
    #pragma unroll
    for (int j = 0; j < NC; ++j) sc[j] = b0[j] * nu1 + b1[j] * nu0;
    #pragma unroll
    for (int i = 0; i < NC; ++i) t8a[i] = 0.f;
    #pragma unroll
    for (int j = 0; j < NC; ++j) fma10(t8a, acol[j], sc[j]);
    mul10(t8a, ld12(&sBT[x8a][0]));
    const float nu8a = sum10(t8a);

    // leaf pair b -> unnormalized L8b
    unpack10(b0, ld12(&sBTpi[xl2][0]));
    unpack10(b1, ld12(&sBTpi[xl3][0]));
    nu0 = sum10(b0); nu1 = sum10(b1);
    #pragma unroll
    for (int j = 0; j < NC; ++j) sc[j] = b0[j] * nu1 + b1[j] * nu0;
    #pragma unroll
    for (int i = 0; i < NC; ++i) t8b[i] = 0.f;
    #pragma unroll
    for (int j = 0; j < NC; ++j) fma10(t8b, acol[j], sc[j]);
    mul10(t8b, ld12(&sBT[x8b][0]));
    const float nu8b = sum10(t8b);

    // L7: cross-scale the two unnormalized L8s, one A-pass
    #pragma unroll
    for (int j = 0; j < NC; ++j) sc[j] = t8a[j] * nu8b + t8b[j] * nu8a;
    float t7[NC];
    #pragma unroll
    for (int i = 0; i < NC; ++i) t7[i] = 0.f;
    #pragma unroll
    for (int j = 0; j < NC; ++j) fma10(t7, acol[j], sc[j]);
    mul10(t7, ld12(&sBT[x7][0]));
    const float nu7 = sum10(t7);
    const float r = RCPF(nu7);
    #pragma unroll
    for (int j = 0; j < NC; ++j) b7out[j] = t7[j] * r;
    return __logf(nu7);
}

// fused 2-level tail step, in place (stride 64), telescoped (1 log, 1 rcp).
__device__ __forceinline__ float fused_step_ip(const F12* acol, const float (*sBT)[NCP],
                                               float* buf, int l,
                                               int xc0, int xc1, int xp)
{
    float t0[NC], t1[NC];
    #pragma unroll
    for (int i = 0; i < NC; ++i) { t0[i] = 0.f; t1[i] = 0.f; }
    #pragma unroll
    for (int j = 0; j < NC; ++j) {
        float4 gv = *(const float4*)(buf + j * 64 + 4 * l);
        fma10(t0, acol[j], gv.x + gv.y);
        fma10(t1, acol[j], gv.z + gv.w);
    }
    mul10(t0, ld12(&sBT[xc0][0]));
    mul10(t1, ld12(&sBT[xc1][0]));
    const float nu0 = sum10(t0), nu1 = sum10(t1);
    float tp[NC];
    #pragma unroll
    for (int i = 0; i < NC; ++i) tp[i] = 0.f;
    #pragma unroll
    for (int j = 0; j < NC; ++j) fma10(tp, acol[j], t0[j] * nu1 + t1[j] * nu0);
    mul10(tp, ld12(&sBT[xp][0]));
    const float nup = sum10(tp);
    const float rp = RCPF(nup);
    #pragma unroll
    for (int j = 0; j < NC; ++j) buf[j * 64 + l] = tp[j] * rp;
    return __logf(nup);   // = log nu_p + log nu0 + log nu1 exactly
}

// ---------------- single fused kernel ----------------
// block = 256 threads = 4 (tree,g) units (one wave each, same g per block).
// Lane = one L6 subtree SEQUENTIALLY in registers; A in 30 VGPRs.
// Head: two 7-node telescoped halves + L6 => 3 logs + 3 rcps per lane.
// Setup: ONE barrier — Pi softmax computed per-thread so each wave folds
// pi into its own B-row writes (no separate sBTpi pass).
// VGPR DISCIPLINE: keep peak live state ~100 (<=128 tier). R13 showed 136
// VGPR drops occupancy to 3 waves/SIMD (41 µs); R7 showed launch_bounds
// min-waves caps cause 600MB scratch spill. Neither is reintroduced.
__global__ __launch_bounds__(256)
void htmm_fused(const int* __restrict__ x,
                const float* __restrict__ A,
                const float* __restrict__ B,
                const float* __restrict__ Pi,
                float* __restrict__ out)
{
    __shared__ __align__(16) float sACol[NC][NCP];   // 0.5*smA[i][j], col-major
    __shared__ __align__(16) float sBT[NM][NCP];     // smB^T rows
    __shared__ __align__(16) float sBTpi[NM][NCP];   // pi (.) smB^T rows (leaves)
    __shared__ __align__(16) float sB6[4][NC][64];   // per-unit SoA; tail in place

    const int bid = blockIdx.x;
    const int g = bid >> 8;
    const int treeBase = (bid & 255) * 4;
    const int tid = threadIdx.x;
    const int u = tid >> 6, lane = tid & 63;

    const int tree = treeBase + u;
    const int tb = tree * NPT;

    // ---- hoisted observation-index loads (overlap setup latency) ----
    int xl[8];
    #pragma unroll
    for (int k = 0; k < 8; ++k) xl[k] = x[tb + 511 + 8 * lane + k];
    int x8v[4];
    #pragma unroll
    for (int c = 0; c < 4; ++c) x8v[c] = x[tb + 255 + 4 * lane + c];
    const int x7a = x[tb + 127 + 2 * lane];
    const int x7b = x[tb + 128 + 2 * lane];
    const int x6v = x[tb + 63 + lane];

    // ---- Pi softmax, PER-THREAD (uniform loads; removes 2nd barrier) ----
    float piv[NC];
    {
        float mx = -1e30f;
        #pragma unroll
        for (int i = 0; i < NC; ++i) { piv[i] = Pi[i * NGEN + g]; mx = fmaxf(mx, piv[i]); }
        float sm = 0.f;
        #pragma unroll
        for (int i = 0; i < NC; ++i) { piv[i] = __expf(piv[i] - mx); sm += piv[i]; }
        const float rs = 1.f / sm;
        #pragma unroll
        for (int i = 0; i < NC; ++i) piv[i] *= rs;
    }

    // ---- B row softmax (no-max: |2.5*N| small, exp safe — R11-validated);
    //      each wave writes BOTH tables for its rows (pi fold from piv) ----
    for (int c = u; c < NC; c += 4) {
        float e0 = __expf(B[(c * NM + lane) * NGEN + g]);
        float e1 = __expf(B[(c * NM + lane + 64) * NGEN + g]);
        float sm = e0 + e1;
        #pragma unroll
        for (int off = 32; off; off >>= 1) sm += __shfl_xor(sm, off);
        const float rs = 1.f / sm;
        const float v0 = e0 * rs, v1 = e1 * rs;
        sBT[lane][c]        = v0;
        sBT[lane + 64][c]   = v1;
        sBTpi[lane][c]      = piv[c] * v0;
        sBTpi[lane + 64][c] = piv[c] * v1;
    }
    if (tid >= 128 && tid < 128 + NC) {   // A column softmax on wave 2
        const int j = tid - 128;
        float col[NC], mx = -1e30f;
        #pragma unroll
        for (int i = 0; i < NC; ++i) { col[i] = A[(i * NC + j) * NGEN + g]; mx = fmaxf(mx, col[i]); }
        float sm = 0.f;
        #pragma unroll
        for (int i = 0; i < NC; ++i) { col[i] = __expf(col[i] - mx); sm += col[i]; }
        const float rs = 0.5f / sm;
        #pragma unroll
        for (int i = 0; i < NC; ++i) sACol[j][i] = col[i] * rs;
    }
    __syncthreads();   // the ONLY block barrier

    // ---- hoist A into registers (one-time broadcast reads) ----
    F12 acol[NC];
    #pragma unroll
    for (int j = 0; j < NC; ++j) acol[j] = ld12(&sACol[j][0]);

    // ---- head: two telescoped halves, then L6 ----
    float b7a[NC], b7b[NC];
    float llacc;
    llacc  = half_subtree(acol, sBT, sBTpi, xl[0], xl[1], xl[2], xl[3],
                          x8v[0], x8v[1], x7a, b7a);
    llacc += half_subtree(acol, sBT, sBTpi, xl[4], xl[5], xl[6], xl[7],
                          x8v[2], x8v[3], x7b, b7b);

    {   // L6: one A-pass on (b7a + b7b)
        float sc[NC], t6[NC];
        #pragma unroll
        for (int j = 0; j < NC; ++j) sc[j] = b7a[j] + b7b[j];
        #pragma unroll
        for (int i = 0; i < NC; ++i) t6[i] = 0.f;
        #pragma unroll
        for (int j = 0; j < NC; ++j) fma10(t6, acol[j], sc[j]);
        mul10(t6, ld12(&sBT[x6v][0]));
        const float nup = sum10(t6);
        llacc += __logf(nup);
        const float rp = RCPF(nup);
        #pragma unroll
        for (int j = 0; j < NC; ++j) sB6[u][j][lane] = t6[j] * rp;
    }

    // ---- tail: levels 5..0, wave-local, in place in sB6 ----
    WAVE_FENCE();
    float lla = 0.f;
    if (lane < 16)
        lla = fused_step_ip(acol, sBT, &sB6[u][0][0], lane,
                            x[tb + 31 + 2 * lane], x[tb + 32 + 2 * lane],
                            x[tb + 15 + lane]);
    llacc += lla;
    WAVE_FENCE();
    float llb = 0.f;
    if (lane < 4)
        llb = fused_step_ip(acol, sBT, &sB6[u][0][0], lane,
                            x[tb + 7 + 2 * lane], x[tb + 8 + 2 * lane],
                            x[tb + 3 + lane]);
    llacc += llb;
    WAVE_FENCE();
    if (lane == 0)
        llacc += fused_step_ip(acol, sBT, &sB6[u][0][0], 0,
                               x[tb + 1], x[tb + 2], x[tb + 0]);

    // ---- full-wave reduce; lane 0 writes the unit's output ----
    #pragma unroll
    for (int off = 32; off; off >>= 1) llacc += __shfl_down(llacc, off);
    if (lane == 0) out[tree * NGEN + g] = llacc;
}

extern "C" void kernel_launch(void* const* d_in, const int* in_sizes, int n_in,
                              void* d_out, int out_size, void* d_ws, size_t ws_size,
                              hipStream_t stream) {
    const int*   x  = (const int*)d_in[0];
    const float* A  = (const float*)d_in[1];
    const float* B  = (const float*)d_in[2];
    const float* Pi = (const float*)d_in[3];
    float* out = (float*)d_out;
    htmm_fused<<<NTREES, 256, 0, stream>>>(x, A, B, Pi, out);
}